// Round 1
// baseline (12327.477 us; speedup 1.0000x reference)
//
#include <hip/hip_runtime.h>
#include <hip/hip_bf16.h>

// ---------------------------------------------------------------------------
// LSTM (B=128, T=512, I=H=1024) + final FC (O=256) on gfx950.
// Pipeline: prep (bf16-convert + gate-permute) -> gemm_xg (x@w_ih^T+bias, bf16,
// time-major) -> lstm_rec (persistent 128-block kernel, flag-sync per step,
// c in registers) -> fc_out.
// Gate permutation: permuted row n = in*64 + g*16 + jl  <->  orig row g*1024 + in*16 + jl
// so one 64-row tile holds all 4 gates of 16 h-columns.
// ---------------------------------------------------------------------------

typedef float  v4f  __attribute__((ext_vector_type(4)));
typedef __bf16 v8bf __attribute__((ext_vector_type(8)));
typedef __bf16 v4bf __attribute__((ext_vector_type(4)));

#define NBLK_REC 128   // recurrence blocks: 2 m-halves x 64 n-tiles (64 gates)

// ---------------- workspace layout (bytes) ----------------
// xg     : 512*128*4096 bf16  = 536870912   (time-major [T][B][4H], permuted cols)
// w_ihp  : 4096*1024 bf16     = 8388608
// w_hhp  : 4096*1024 bf16     = 8388608
// biasp  : 4096 f32           = 16384
// hbuf   : 2*128*1024 bf16    = 524288
// cnt    : 513 i32            = 2052
static constexpr size_t XG_B    = (size_t)512 * 128 * 4096 * 2;
static constexpr size_t WIHP_O  = XG_B;
static constexpr size_t WHHP_O  = WIHP_O + (size_t)4096 * 1024 * 2;
static constexpr size_t BIASP_O = WHHP_O + (size_t)4096 * 1024 * 2;
static constexpr size_t HBUF_O  = BIASP_O + 16384;
static constexpr size_t CNT_O   = HBUF_O + (size_t)2 * 128 * 1024 * 2;

// ---------------------------------------------------------------------------
// prep: convert+permute weights, convert h0, zero flags
// grid 16384 x 256 = 4,194,304 threads (= 4096*1024)
// ---------------------------------------------------------------------------
__global__ __launch_bounds__(256) void prep_kernel(
    const float* __restrict__ w_ih, const float* __restrict__ w_hh,
    const float* __restrict__ bias, const float* __restrict__ h0,
    __bf16* __restrict__ w_ihp, __bf16* __restrict__ w_hhp,
    float* __restrict__ biasp, __bf16* __restrict__ hb0, int* __restrict__ cnt)
{
    const int idx = blockIdx.x * 256 + threadIdx.x;       // 0 .. 4194303
    const int n = idx >> 10, k = idx & 1023;
    const int on = ((n >> 4) & 3) * 1024 + (n >> 6) * 16 + (n & 15);
    w_ihp[idx] = (__bf16)w_ih[(size_t)on * 1024 + k];
    w_hhp[idx] = (__bf16)w_hh[(size_t)on * 1024 + k];
    if (idx < 4096) {
        const int obn = ((idx >> 4) & 3) * 1024 + (idx >> 6) * 16 + (idx & 15);
        biasp[idx] = bias[obn];
    }
    if (idx < 128 * 1024) hb0[idx] = (__bf16)h0[idx];
    if (idx < 513) cnt[idx] = (idx == 0) ? NBLK_REC : 0;
}

// ---------------------------------------------------------------------------
// gemm_xg: xg[t][b][n] = bf16( sum_k x[b][t][k]*w_ihp[n][k] + biasp[n] )
// M = B*T = 65536 (m = b*512+t), N = 4096, K = 1024.
// 128x128 tile, 4 waves (2x2), wave 64x64 as 4x4 MFMA 16x16x32.
// A staged fp32->bf16 explicitly; both LDS tiles padded (pitch 40 elem) ->
// conflict-free-ish frag reads.
// ---------------------------------------------------------------------------
__global__ __launch_bounds__(256) void gemm_xg(
    const float* __restrict__ x, const __bf16* __restrict__ wih,
    const float* __restrict__ biasp, __bf16* __restrict__ xg)
{
    const int bx = blockIdx.x;
    const int mtile = bx >> 5, ntile = bx & 31;
    const int m0 = mtile << 7, n0 = ntile << 7;
    const int bb = mtile >> 2, t0 = (mtile & 3) << 7;

    const int tid = threadIdx.x;
    const int lane = tid & 63, wave = tid >> 6;
    const int wm = wave >> 1, wn = wave & 1;
    const int l15 = lane & 15, q = lane >> 4;

    __shared__ __bf16 Al[128][40];
    __shared__ __bf16 Bl[128][40];

    v4f acc[4][4] = {};

    for (int kt = 0; kt < 32; ++kt) {
        __syncthreads();
        const int k0 = kt * 32;
        #pragma unroll
        for (int i = 0; i < 4; ++i) {                 // A: 128x32 fp32 -> bf16
            const int s = tid + i * 256, r = s >> 3, c = s & 7;
            const float4 v = *(const float4*)&x[(size_t)(m0 + r) * 1024 + k0 + c * 4];
            v4bf pk = { (__bf16)v.x, (__bf16)v.y, (__bf16)v.z, (__bf16)v.w };
            *(v4bf*)&Al[r][c * 4] = pk;
        }
        #pragma unroll
        for (int j = 0; j < 2; ++j) {                 // B: 128x32 bf16
            const int s = tid + j * 256, r = s >> 2, ch = s & 3;
            const uint4 v = *(const uint4*)&wih[(size_t)(n0 + r) * 1024 + k0 + ch * 8];
            *(uint4*)&Bl[r][ch * 8] = v;
        }
        __syncthreads();
        v8bf a[4], b[4];
        #pragma unroll
        for (int im = 0; im < 4; ++im) a[im] = *(const v8bf*)&Al[wm * 64 + im * 16 + l15][q * 8];
        #pragma unroll
        for (int in = 0; in < 4; ++in) b[in] = *(const v8bf*)&Bl[wn * 64 + in * 16 + l15][q * 8];
        #pragma unroll
        for (int im = 0; im < 4; ++im)
            #pragma unroll
            for (int in = 0; in < 4; ++in)
                acc[im][in] = __builtin_amdgcn_mfma_f32_16x16x32_bf16(a[im], b[in], acc[im][in], 0, 0, 0);
    }
    // epilogue: +bias, cast, store time-major [t][b][n]
    #pragma unroll
    for (int in = 0; in < 4; ++in) {
        const int nl = wn * 64 + in * 16 + l15;
        const float bv = biasp[n0 + nl];
        #pragma unroll
        for (int im = 0; im < 4; ++im) {
            const int mbase = wm * 64 + im * 16 + q * 4;
            #pragma unroll
            for (int r = 0; r < 4; ++r) {
                const int t = t0 + mbase + r;
                xg[((size_t)t * 128 + bb) * 4096 + n0 + nl] = (__bf16)(acc[im][in][r] + bv);
            }
        }
    }
}

// ---------------------------------------------------------------------------
// lstm_rec: persistent kernel, 128 blocks = 2 m-halves x 64 n-tiles(64 gates).
// Per step: gates(64x64) = h(t-1)[64x1024] @ whh_tile^T, + xg, pointwise,
// write h-tile, release-publish; consumers acquire-fence then read.
// Block: 4 waves 2x2, wave tile 32x32 (2x2 MFMA 16x16x32).
// B staged per K-iter (BK=128) via reg double-buffer; A (h) direct global,
// prefetched one BK ahead. c kept in registers all 512 steps.
// ---------------------------------------------------------------------------
__global__ __launch_bounds__(256) void lstm_rec(
    const __bf16* __restrict__ whh, const __bf16* __restrict__ xg,
    const float* __restrict__ c0, __bf16* __restrict__ hbuf, int* cnt)
{
    const int tid = threadIdx.x;
    const int lane = tid & 63, wave = tid >> 6;
    const int imh = blockIdx.x >> 6;     // m-half (0..1)
    const int in  = blockIdx.x & 63;     // n-tile (0..63)
    const int wm = wave >> 1, wn = wave & 1;
    const int l15 = lane & 15, q = lane >> 4;

    __shared__ __bf16 Bst[2][64][136];   // BK=128 tile, padded pitch
    __shared__ float glds[64][68];       // gate exchange

    // epilogue mapping: thread -> (m-row, 4 h-cols)
    const int mL  = tid >> 2;
    const int jl4 = (tid & 3) << 2;
    const int mG  = imh * 64 + mL;
    const int jG  = in * 16 + jl4;

    const float4 cini = *(const float4*)&c0[(size_t)mG * 1024 + jG];
    float c_[4] = { cini.x, cini.y, cini.z, cini.w };

    int br[4], bch[4];
    #pragma unroll
    for (int i = 0; i < 4; ++i) { const int s = tid + i * 256; br[i] = s >> 4; bch[i] = s & 15; }
    const __bf16* wbase = whh + (size_t)in * 64 * 1024;
    const int aRow0 = wm * 32 + l15;

    #pragma unroll 1
    for (int t = 1; t <= 512; ++t) {
        // ---- wait for h(t-1) ----
        if (tid == 0) {
            while (__hip_atomic_load(&cnt[t - 1], __ATOMIC_RELAXED, __HIP_MEMORY_SCOPE_AGENT) < NBLK_REC)
                __builtin_amdgcn_s_sleep(1);
        }
        __syncthreads();
        __builtin_amdgcn_fence(__ATOMIC_ACQUIRE, "agent");   // invalidate stale h lines

        const __bf16* hrd = hbuf + (size_t)((t - 1) & 1) * 131072 + (size_t)imh * 65536;

        v4f acc00 = {}, acc01 = {}, acc10 = {}, acc11 = {};
        uint4 sreg[4];
        v8bf aN[8];
        #pragma unroll
        for (int i = 0; i < 4; ++i)
            sreg[i] = *(const uint4*)&wbase[(size_t)br[i] * 1024 + bch[i] * 8];
        #pragma unroll
        for (int k32 = 0; k32 < 4; ++k32) {
            aN[k32 * 2 + 0] = *(const v8bf*)&hrd[(size_t)aRow0 * 1024 + k32 * 32 + q * 8];
            aN[k32 * 2 + 1] = *(const v8bf*)&hrd[(size_t)(aRow0 + 16) * 1024 + k32 * 32 + q * 8];
        }
        #pragma unroll
        for (int kt = 0; kt < 8; ++kt) {
            const int buf = kt & 1;
            #pragma unroll
            for (int i = 0; i < 4; ++i) *(uint4*)&Bst[buf][br[i]][bch[i] * 8] = sreg[i];
            __syncthreads();
            v8bf aC[8];
            #pragma unroll
            for (int i = 0; i < 8; ++i) aC[i] = aN[i];
            if (kt < 7) {   // prefetch next BK
                #pragma unroll
                for (int i = 0; i < 4; ++i)
                    sreg[i] = *(const uint4*)&wbase[(size_t)br[i] * 1024 + (kt + 1) * 128 + bch[i] * 8];
                #pragma unroll
                for (int k32 = 0; k32 < 4; ++k32) {
                    aN[k32 * 2 + 0] = *(const v8bf*)&hrd[(size_t)aRow0 * 1024 + (kt + 1) * 128 + k32 * 32 + q * 8];
                    aN[k32 * 2 + 1] = *(const v8bf*)&hrd[(size_t)(aRow0 + 16) * 1024 + (kt + 1) * 128 + k32 * 32 + q * 8];
                }
            }
            #pragma unroll
            for (int k32 = 0; k32 < 4; ++k32) {
                const v8bf b0 = *(const v8bf*)&Bst[buf][wn * 32 + l15][k32 * 32 + q * 8];
                const v8bf b1 = *(const v8bf*)&Bst[buf][wn * 32 + 16 + l15][k32 * 32 + q * 8];
                acc00 = __builtin_amdgcn_mfma_f32_16x16x32_bf16(aC[k32 * 2 + 0], b0, acc00, 0, 0, 0);
                acc01 = __builtin_amdgcn_mfma_f32_16x16x32_bf16(aC[k32 * 2 + 0], b1, acc01, 0, 0, 0);
                acc10 = __builtin_amdgcn_mfma_f32_16x16x32_bf16(aC[k32 * 2 + 1], b0, acc10, 0, 0, 0);
                acc11 = __builtin_amdgcn_mfma_f32_16x16x32_bf16(aC[k32 * 2 + 1], b1, acc11, 0, 0, 0);
            }
        }
        // ---- epilogue: gates -> LDS, pointwise LSTM cell, publish h ----
        #pragma unroll
        for (int r = 0; r < 4; ++r) {
            glds[wm * 32 + q * 4 + r][wn * 32 + l15]           = acc00[r];
            glds[wm * 32 + q * 4 + r][wn * 32 + 16 + l15]      = acc01[r];
            glds[wm * 32 + 16 + q * 4 + r][wn * 32 + l15]      = acc10[r];
            glds[wm * 32 + 16 + q * 4 + r][wn * 32 + 16 + l15] = acc11[r];
        }
        __syncthreads();
        const __bf16* xgr = xg + ((size_t)(t - 1) * 128 + mG) * 4096 + in * 64;
        float gv[4][4];
        #pragma unroll
        for (int g = 0; g < 4; ++g) {
            const v4bf xv = *(const v4bf*)&xgr[g * 16 + jl4];
            #pragma unroll
            for (int i2 = 0; i2 < 4; ++i2)
                gv[g][i2] = glds[mL][g * 16 + jl4 + i2] + (float)xv[i2];
        }
        v4bf ho;
        #pragma unroll
        for (int i2 = 0; i2 < 4; ++i2) {
            const float ig = 1.f / (1.f + __expf(-gv[0][i2]));
            const float fg = 1.f / (1.f + __expf(-gv[1][i2]));
            const float cg = 1.f - 2.f / (__expf(2.f * gv[2][i2]) + 1.f);
            const float og = 1.f / (1.f + __expf(-gv[3][i2]));
            c_[i2] = fg * c_[i2] + ig * cg;
            const float th = 1.f - 2.f / (__expf(2.f * c_[i2]) + 1.f);
            ho[i2] = (__bf16)(og * th);
        }
        __bf16* hwr = hbuf + (size_t)(t & 1) * 131072 + (size_t)mG * 1024 + jG;
        *(v4bf*)hwr = ho;
        __syncthreads();   // drains all threads' vmem stores (vmcnt(0) before barrier)
        if (tid == 0)
            __hip_atomic_fetch_add(&cnt[t], 1, __ATOMIC_RELEASE, __HIP_MEMORY_SCOPE_AGENT);
    }
}

// ---------------------------------------------------------------------------
// fc_out: out[b][o] = h_last[b] . w_fc[o] + b_fc[o]   (h_last = hbuf[0], bf16)
// ---------------------------------------------------------------------------
__global__ __launch_bounds__(256) void fc_out(
    const __bf16* __restrict__ hb, const float* __restrict__ wfc,
    const float* __restrict__ bfc, float* __restrict__ out)
{
    const int b = blockIdx.x, o = threadIdx.x;
    __shared__ float hs[1024];
    for (int i = threadIdx.x; i < 1024; i += 256) hs[i] = (float)hb[(size_t)b * 1024 + i];
    __syncthreads();
    const float* wr = wfc + (size_t)o * 1024;
    float s = 0.f;
    for (int k = 0; k < 1024; k += 4) {
        const float4 w = *(const float4*)&wr[k];
        s += hs[k] * w.x + hs[k + 1] * w.y + hs[k + 2] * w.z + hs[k + 3] * w.w;
    }
    out[b * 256 + o] = s + bfc[o];
}

// ---------------------------------------------------------------------------
extern "C" void kernel_launch(void* const* d_in, const int* in_sizes, int n_in,
                              void* d_out, int out_size, void* d_ws, size_t ws_size,
                              hipStream_t stream) {
    (void)in_sizes; (void)n_in; (void)out_size; (void)ws_size;
    const float* x    = (const float*)d_in[0];
    const float* h0   = (const float*)d_in[1];
    const float* c0   = (const float*)d_in[2];
    const float* w_ih = (const float*)d_in[3];
    const float* w_hh = (const float*)d_in[4];
    const float* bias = (const float*)d_in[5];
    const float* w_fc = (const float*)d_in[6];
    const float* b_fc = (const float*)d_in[7];
    float* out = (float*)d_out;

    char* ws = (char*)d_ws;
    __bf16* xg    = (__bf16*)(ws);
    __bf16* w_ihp = (__bf16*)(ws + WIHP_O);
    __bf16* w_hhp = (__bf16*)(ws + WHHP_O);
    float*  biasp = (float*)(ws + BIASP_O);
    __bf16* hbuf  = (__bf16*)(ws + HBUF_O);
    int*    cnt   = (int*)(ws + CNT_O);

    prep_kernel<<<16384, 256, 0, stream>>>(w_ih, w_hh, bias, h0, w_ihp, w_hhp, biasp, hbuf, cnt);
    gemm_xg<<<16384, 256, 0, stream>>>(x, w_ihp, biasp, xg);
    lstm_rec<<<NBLK_REC, 256, 0, stream>>>(w_hhp, xg, c0, hbuf, cnt);
    fc_out<<<128, 256, 0, stream>>>(hbuf, w_fc, b_fc, out);
}

// Round 2
// 5999.870 us; speedup vs baseline: 2.0546x; 2.0546x over previous
//
#include <hip/hip_runtime.h>
#include <hip/hip_bf16.h>

// ---------------------------------------------------------------------------
// LSTM (B=128, T=512, I=H=1024) + final FC (O=256) on gfx950.
// prep -> gemm_xg (x@w_ih^T+bias, bf16, time-major) -> lstm_rec -> fc_out.
//
// lstm_rec v2: 256 persistent blocks (1/CU), tile M=32 x N=64(gates), 4 waves
// K-split (256 k each). w_hh tile lives in VGPRs (128/lane) for all 512 steps.
// Cross-block h exchange via RELAXED agent-scope (sc1) atomics only -- no
// release/acquire fences, hence no buffer_wbl2 / buffer_inv L2 walks (the
// 20.9us/step killer in v1). h stores are sc1 write-through to L3; producers
// drain via the vmcnt(0) in __syncthreads, then relaxed-atomicAdd the step
// flag; consumers sc1-poll the flag and sc1-load h straight from L3.
// Gate permutation: permuted row n = in*64 + g*16 + jl (16 h-cols per n-tile).
// ---------------------------------------------------------------------------

typedef float  v4f  __attribute__((ext_vector_type(4)));
typedef __bf16 v8bf __attribute__((ext_vector_type(8)));
typedef __bf16 v4bf __attribute__((ext_vector_type(4)));
typedef __bf16 v2bf __attribute__((ext_vector_type(2)));

#define NBLK_REC 256   // 4 m-quarters x 64 n-tiles

// ---------------- workspace layout (bytes) ----------------
static constexpr size_t XG_B    = (size_t)512 * 128 * 4096 * 2;   // 512 MiB
static constexpr size_t WIHP_O  = XG_B;
static constexpr size_t WHHP_O  = WIHP_O + (size_t)4096 * 1024 * 2;
static constexpr size_t BIASP_O = WHHP_O + (size_t)4096 * 1024 * 2;
static constexpr size_t HBUF_O  = BIASP_O + 16384;
static constexpr size_t CNT_O   = HBUF_O + (size_t)2 * 128 * 1024 * 2;

// ---------------------------------------------------------------------------
// prep: convert+permute weights, convert h0, init flags
// ---------------------------------------------------------------------------
__global__ __launch_bounds__(256) void prep_kernel(
    const float* __restrict__ w_ih, const float* __restrict__ w_hh,
    const float* __restrict__ bias, const float* __restrict__ h0,
    __bf16* __restrict__ w_ihp, __bf16* __restrict__ w_hhp,
    float* __restrict__ biasp, __bf16* __restrict__ hb0, int* __restrict__ cnt)
{
    const int idx = blockIdx.x * 256 + threadIdx.x;       // 0 .. 4194303
    const int n = idx >> 10, k = idx & 1023;
    const int on = ((n >> 4) & 3) * 1024 + (n >> 6) * 16 + (n & 15);
    w_ihp[idx] = (__bf16)w_ih[(size_t)on * 1024 + k];
    w_hhp[idx] = (__bf16)w_hh[(size_t)on * 1024 + k];
    if (idx < 4096) {
        const int obn = ((idx >> 4) & 3) * 1024 + (idx >> 6) * 16 + (idx & 15);
        biasp[idx] = bias[obn];
    }
    if (idx < 128 * 1024) hb0[idx] = (__bf16)h0[idx];
    if (idx < 513) cnt[idx] = (idx == 0) ? NBLK_REC : 0;
}

// ---------------------------------------------------------------------------
// gemm_xg: xg[t][b][n] = bf16( sum_k x[b][t][k]*w_ihp[n][k] + biasp[n] )
// (unchanged from R1; ~1.5ms -- optimize after counters are visible)
// ---------------------------------------------------------------------------
__global__ __launch_bounds__(256) void gemm_xg(
    const float* __restrict__ x, const __bf16* __restrict__ wih,
    const float* __restrict__ biasp, __bf16* __restrict__ xg)
{
    const int bx = blockIdx.x;
    const int mtile = bx >> 5, ntile = bx & 31;
    const int m0 = mtile << 7, n0 = ntile << 7;
    const int bb = mtile >> 2, t0 = (mtile & 3) << 7;

    const int tid = threadIdx.x;
    const int lane = tid & 63, wave = tid >> 6;
    const int wm = wave >> 1, wn = wave & 1;
    const int l15 = lane & 15, q = lane >> 4;

    __shared__ __bf16 Al[128][40];
    __shared__ __bf16 Bl[128][40];

    v4f acc[4][4] = {};

    for (int kt = 0; kt < 32; ++kt) {
        __syncthreads();
        const int k0 = kt * 32;
        #pragma unroll
        for (int i = 0; i < 4; ++i) {                 // A: 128x32 fp32 -> bf16
            const int s = tid + i * 256, r = s >> 3, c = s & 7;
            const float4 v = *(const float4*)&x[(size_t)(m0 + r) * 1024 + k0 + c * 4];
            v4bf pk = { (__bf16)v.x, (__bf16)v.y, (__bf16)v.z, (__bf16)v.w };
            *(v4bf*)&Al[r][c * 4] = pk;
        }
        #pragma unroll
        for (int j = 0; j < 2; ++j) {                 // B: 128x32 bf16
            const int s = tid + j * 256, r = s >> 2, ch = s & 3;
            const uint4 v = *(const uint4*)&wih[(size_t)(n0 + r) * 1024 + k0 + ch * 8];
            *(uint4*)&Bl[r][ch * 8] = v;
        }
        __syncthreads();
        v8bf a[4], b[4];
        #pragma unroll
        for (int im = 0; im < 4; ++im) a[im] = *(const v8bf*)&Al[wm * 64 + im * 16 + l15][q * 8];
        #pragma unroll
        for (int in = 0; in < 4; ++in) b[in] = *(const v8bf*)&Bl[wn * 64 + in * 16 + l15][q * 8];
        #pragma unroll
        for (int im = 0; im < 4; ++im)
            #pragma unroll
            for (int in = 0; in < 4; ++in)
                acc[im][in] = __builtin_amdgcn_mfma_f32_16x16x32_bf16(a[im], b[in], acc[im][in], 0, 0, 0);
    }
    #pragma unroll
    for (int in = 0; in < 4; ++in) {
        const int nl = wn * 64 + in * 16 + l15;
        const float bv = biasp[n0 + nl];
        #pragma unroll
        for (int im = 0; im < 4; ++im) {
            const int mbase = wm * 64 + im * 16 + q * 4;
            #pragma unroll
            for (int r = 0; r < 4; ++r) {
                const int t = t0 + mbase + r;
                xg[((size_t)t * 128 + bb) * 4096 + n0 + nl] = (__bf16)(acc[im][in][r] + bv);
            }
        }
    }
}

// ---------------------------------------------------------------------------
// lstm_rec v2 (see header comment)
// ---------------------------------------------------------------------------
__device__ __forceinline__ v8bf ld_frag_sc1(const unsigned long long* p) {
    union { unsigned long long u[2]; v8bf v; } c;
    c.u[0] = __hip_atomic_load(p,     __ATOMIC_RELAXED, __HIP_MEMORY_SCOPE_AGENT);
    c.u[1] = __hip_atomic_load(p + 1, __ATOMIC_RELAXED, __HIP_MEMORY_SCOPE_AGENT);
    return c.v;
}

__device__ __forceinline__ float sigm_f(float x) {
    return __builtin_amdgcn_rcpf(1.f + __expf(-x));
}
__device__ __forceinline__ float tanh_f(float x) {
    return 1.f - 2.f * __builtin_amdgcn_rcpf(__expf(2.f * x) + 1.f);
}

__global__ __launch_bounds__(256, 1) void lstm_rec(
    const __bf16* __restrict__ whh, const __bf16* __restrict__ xg,
    const float* __restrict__ c0, __bf16* __restrict__ hbuf, int* cnt)
{
    const int tid  = threadIdx.x;
    const int lane = tid & 63, kw = tid >> 6;   // wave index = K-slice (256 k)
    const int in   = blockIdx.x & 63;           // n-tile: 64 gate cols = 16 h cols
    const int mq   = blockIdx.x >> 6;           // m-quarter: 32 rows
    const int l15  = lane & 15, q = lane >> 4;

    __shared__ float pbuf[4][32][68];           // K-split partials, 34.8 KiB

    // ---- B (w_hh tile) into registers, once: breg[nf][ks], 128 VGPRs ----
    v8bf breg[4][8];
    {
        const __bf16* wb = whh + ((size_t)in * 64) * 1024 + kw * 256;
        #pragma unroll
        for (int nf = 0; nf < 4; ++nf)
            #pragma unroll
            for (int ks = 0; ks < 8; ++ks)
                breg[nf][ks] = *(const v8bf*)&wb[(size_t)(nf * 16 + l15) * 1024 + ks * 32 + q * 8];
    }

    // epilogue mapping: thread -> (m-row em, 2 h-cols at ehc)
    const int em  = tid >> 3;                   // 0..31
    const int ehc = (tid & 7) * 2;              // 0,2,..,14
    const int mG  = mq * 32 + em;
    const int jG  = in * 16 + ehc;

    float2 cv = *(const float2*)&c0[(size_t)mG * 1024 + jG];

    // A-fragment addressing in 8-byte units: row*256 + kw*64 + ks*8 + q*2
    const size_t rb0 = (size_t)(mq * 32 + l15) * 256 + (size_t)kw * 64 + q * 2;
    const size_t rb1 = rb0 + 16 * 256;

    #pragma unroll 1
    for (int t = 1; t <= 512; ++t) {
        // prefetch xg for this step (independent of the flag)
        v2bf xpre[4];
        {
            const __bf16* xgp = xg + ((size_t)(t - 1) * 128 + mG) * 4096 + in * 64;
            #pragma unroll
            for (int g = 0; g < 4; ++g) xpre[g] = *(const v2bf*)&xgp[g * 16 + ehc];
        }

        // ---- wait for h(t-1) (relaxed sc1 poll; no fences) ----
        if (tid == 0) {
            while (__hip_atomic_load(&cnt[t - 1], __ATOMIC_RELAXED, __HIP_MEMORY_SCOPE_AGENT) < NBLK_REC)
                __builtin_amdgcn_s_sleep(1);
        }
        __syncthreads();

        const unsigned long long* hq =
            (const unsigned long long*)(hbuf + (size_t)((t - 1) & 1) * 131072);

        // ---- A fragments straight from L3 (sc1), read-once per block ----
        v8bf af[2][8];
        #pragma unroll
        for (int ks = 0; ks < 8; ++ks) {
            af[0][ks] = ld_frag_sc1(hq + rb0 + ks * 8);
            af[1][ks] = ld_frag_sc1(hq + rb1 + ks * 8);
        }

        v4f acc[2][4] = {};
        #pragma unroll
        for (int ks = 0; ks < 8; ++ks)
            #pragma unroll
            for (int mh = 0; mh < 2; ++mh)
                #pragma unroll
                for (int nf = 0; nf < 4; ++nf)
                    acc[mh][nf] = __builtin_amdgcn_mfma_f32_16x16x32_bf16(
                        af[mh][ks], breg[nf][ks], acc[mh][nf], 0, 0, 0);

        // ---- cross-wave K reduction via LDS ----
        #pragma unroll
        for (int mh = 0; mh < 2; ++mh)
            #pragma unroll
            for (int nf = 0; nf < 4; ++nf)
                #pragma unroll
                for (int r = 0; r < 4; ++r)
                    pbuf[kw][mh * 16 + q * 4 + r][nf * 16 + l15] = acc[mh][nf][r];
        __syncthreads();

        float2 gsum[4];
        #pragma unroll
        for (int g = 0; g < 4; ++g) {
            float2 s = *(const float2*)&pbuf[0][em][g * 16 + ehc];
            #pragma unroll
            for (int k2 = 1; k2 < 4; ++k2) {
                const float2 p2 = *(const float2*)&pbuf[k2][em][g * 16 + ehc];
                s.x += p2.x; s.y += p2.y;
            }
            s.x += (float)xpre[g][0];
            s.y += (float)xpre[g][1];
            gsum[g] = s;
        }

        // ---- pointwise cell (c stays in registers) ----
        cv.x = sigm_f(gsum[1].x) * cv.x + sigm_f(gsum[0].x) * tanh_f(gsum[2].x);
        cv.y = sigm_f(gsum[1].y) * cv.y + sigm_f(gsum[0].y) * tanh_f(gsum[2].y);
        const float hx = sigm_f(gsum[3].x) * tanh_f(cv.x);
        const float hy = sigm_f(gsum[3].y) * tanh_f(cv.y);

        union { __bf16 b[2]; unsigned u; } hp;
        hp.b[0] = (__bf16)hx; hp.b[1] = (__bf16)hy;
        __hip_atomic_store(
            (unsigned*)(hbuf + (size_t)(t & 1) * 131072 + (size_t)mG * 1024 + jG),
            hp.u, __ATOMIC_RELAXED, __HIP_MEMORY_SCOPE_AGENT);

        __syncthreads();   // vmcnt(0): every thread's sc1 h-store has reached L3
        if (tid == 0)
            __hip_atomic_fetch_add(&cnt[t], 1, __ATOMIC_RELAXED, __HIP_MEMORY_SCOPE_AGENT);
    }
}

// ---------------------------------------------------------------------------
// fc_out: out[b][o] = h_last[b] . w_fc[o] + b_fc[o]   (h_last = hbuf slot 0)
// ---------------------------------------------------------------------------
__global__ __launch_bounds__(256) void fc_out(
    const __bf16* __restrict__ hb, const float* __restrict__ wfc,
    const float* __restrict__ bfc, float* __restrict__ out)
{
    const int b = blockIdx.x, o = threadIdx.x;
    __shared__ float hs[1024];
    for (int i = threadIdx.x; i < 1024; i += 256) hs[i] = (float)hb[(size_t)b * 1024 + i];
    __syncthreads();
    const float* wr = wfc + (size_t)o * 1024;
    float s = 0.f;
    for (int k = 0; k < 1024; k += 4) {
        const float4 w = *(const float4*)&wr[k];
        s += hs[k] * w.x + hs[k + 1] * w.y + hs[k + 2] * w.z + hs[k + 3] * w.w;
    }
    out[b * 256 + o] = s + bfc[o];
}

// ---------------------------------------------------------------------------
extern "C" void kernel_launch(void* const* d_in, const int* in_sizes, int n_in,
                              void* d_out, int out_size, void* d_ws, size_t ws_size,
                              hipStream_t stream) {
    (void)in_sizes; (void)n_in; (void)out_size; (void)ws_size;
    const float* x    = (const float*)d_in[0];
    const float* h0   = (const float*)d_in[1];
    const float* c0   = (const float*)d_in[2];
    const float* w_ih = (const float*)d_in[3];
    const float* w_hh = (const float*)d_in[4];
    const float* bias = (const float*)d_in[5];
    const float* w_fc = (const float*)d_in[6];
    const float* b_fc = (const float*)d_in[7];
    float* out = (float*)d_out;

    char* ws = (char*)d_ws;
    __bf16* xg    = (__bf16*)(ws);
    __bf16* w_ihp = (__bf16*)(ws + WIHP_O);
    __bf16* w_hhp = (__bf16*)(ws + WHHP_O);
    float*  biasp = (float*)(ws + BIASP_O);
    __bf16* hbuf  = (__bf16*)(ws + HBUF_O);
    int*    cnt   = (int*)(ws + CNT_O);

    prep_kernel<<<16384, 256, 0, stream>>>(w_ih, w_hh, bias, h0, w_ihp, w_hhp, biasp, hbuf, cnt);
    gemm_xg<<<16384, 256, 0, stream>>>(x, w_ihp, biasp, xg);
    lstm_rec<<<NBLK_REC, 256, 0, stream>>>(w_hhp, xg, c0, hbuf, cnt);
    fc_out<<<128, 256, 0, stream>>>(hbuf, w_fc, b_fc, out);
}

// Round 3
// 5963.874 us; speedup vs baseline: 2.0670x; 1.0060x over previous
//
#include <hip/hip_runtime.h>
#include <hip/hip_bf16.h>

// ---------------------------------------------------------------------------
// LSTM (B=128, T=512, I=H=1024) + final FC (O=256) on gfx950.
// prep -> xcast (fp32->bf16) -> gemm_xg (bf16 GEMM, time-major) -> lstm_rec
// -> fc_out.
//
// lstm_rec v3: 256 persistent blocks = 4 m-quarters x 64 n-tiles. w_hh tile in
// VGPRs for all 512 steps; c in registers. Sync per step via per-producer
// ready FLAGS (relaxed sc1 store of 1), per-wave 64-lane poll + __ballot.
// NO atomic RMW (v2's 256-way same-address atomicAdd serialized ~6us/step),
// NO release/acquire fences (v1's buffer_wbl2/inv walks, ~19us/step).
// The 4 m-quarters are independent recurrence chains (batch rows) and sync
// only within their own 64-block group.
// Gate permutation: permuted row n = in*64 + g*16 + jl (16 h-cols per n-tile).
// ---------------------------------------------------------------------------

typedef float  v4f  __attribute__((ext_vector_type(4)));
typedef __bf16 v8bf __attribute__((ext_vector_type(8)));
typedef __bf16 v4bf __attribute__((ext_vector_type(4)));
typedef __bf16 v2bf __attribute__((ext_vector_type(2)));

#define NBLK_REC 256

// ---------------- workspace layout (bytes) ----------------
static constexpr size_t XG_B    = (size_t)512 * 128 * 4096 * 2;      // 512 MiB
static constexpr size_t WIHP_O  = XG_B;
static constexpr size_t WHHP_O  = WIHP_O + (size_t)4096 * 1024 * 2;
static constexpr size_t BIASP_O = WHHP_O + (size_t)4096 * 1024 * 2;
static constexpr size_t HBUF_O  = BIASP_O + 16384;
static constexpr size_t FLAGS_O = HBUF_O + (size_t)2 * 128 * 1024 * 2;
static constexpr size_t XB_O    = FLAGS_O + (size_t)513 * 256 * 4;   // 525312
static constexpr size_t WS_FULL = XB_O + (size_t)128 * 512 * 1024 * 2; // +128MiB

// ---------------------------------------------------------------------------
// prep: convert+permute weights, convert h0, init flags
// ---------------------------------------------------------------------------
__global__ __launch_bounds__(256) void prep_kernel(
    const float* __restrict__ w_ih, const float* __restrict__ w_hh,
    const float* __restrict__ bias, const float* __restrict__ h0,
    __bf16* __restrict__ w_ihp, __bf16* __restrict__ w_hhp,
    float* __restrict__ biasp, __bf16* __restrict__ hb0, int* __restrict__ flags)
{
    const int idx = blockIdx.x * 256 + threadIdx.x;       // 0 .. 4194303
    const int n = idx >> 10, k = idx & 1023;
    const int on = ((n >> 4) & 3) * 1024 + (n >> 6) * 16 + (n & 15);
    w_ihp[idx] = (__bf16)w_ih[(size_t)on * 1024 + k];
    w_hhp[idx] = (__bf16)w_hh[(size_t)on * 1024 + k];
    if (idx < 4096) {
        const int obn = ((idx >> 4) & 3) * 1024 + (idx >> 6) * 16 + (idx & 15);
        biasp[idx] = bias[obn];
    }
    if (idx < 128 * 1024) hb0[idx] = (__bf16)h0[idx];
    if (idx < 513 * 256) flags[idx] = (idx < 256) ? 1 : 0;  // t=0 ready
}

// ---------------------------------------------------------------------------
// xcast: x fp32 -> bf16 (removes per-tile convert redundancy in gemm)
// ---------------------------------------------------------------------------
__global__ __launch_bounds__(256) void xcast(
    const float* __restrict__ x, __bf16* __restrict__ xb)
{
    const size_t i = ((size_t)blockIdx.x * 256 + threadIdx.x) * 8;
    const float4 a = *(const float4*)&x[i];
    const float4 b = *(const float4*)&x[i + 4];
    v8bf o = { (__bf16)a.x, (__bf16)a.y, (__bf16)a.z, (__bf16)a.w,
               (__bf16)b.x, (__bf16)b.y, (__bf16)b.z, (__bf16)b.w };
    *(v8bf*)&xb[i] = o;
}

// ---------------------------------------------------------------------------
// gemm_xg (bf16 A): xg[t][b][n] = bf16( xb[m] . w_ihp[n] + biasp[n] )
// M=65536 (m=b*512+t), N=4096, K=1024. 128x128 tile, 4 waves 2x2, BK=64.
// LDS-buffered epilogue -> coalesced dwordx4 stores.
// ---------------------------------------------------------------------------
__global__ __launch_bounds__(256) void gemm_xg_bf16(
    const __bf16* __restrict__ xb, const __bf16* __restrict__ wih,
    const float* __restrict__ biasp, __bf16* __restrict__ xg)
{
    const int bx = blockIdx.x;
    const int mtile = bx >> 5, ntile = bx & 31;
    const int m0 = mtile << 7, n0 = ntile << 7;
    const int bb = mtile >> 2, t0 = (mtile & 3) << 7;
    const int tid = threadIdx.x;
    const int lane = tid & 63, wave = tid >> 6;
    const int wm = wave >> 1, wn = wave & 1;
    const int l15 = lane & 15, q = lane >> 4;

    __shared__ union {
        struct { __bf16 A[128][72]; __bf16 B[128][72]; } s;  // 36864 B
        __bf16 C[128][132];                                   // 33792 B
    } u;

    const int sr = tid >> 3, sc = (tid & 7) * 8;
    const __bf16* ag = xb  + (size_t)(m0 + sr) * 1024 + sc;
    const __bf16* bg = wih + (size_t)(n0 + sr) * 1024 + sc;

    v4f acc[4][4] = {};
    for (int kt = 0; kt < 16; ++kt) {
        __syncthreads();
        #pragma unroll
        for (int i = 0; i < 4; ++i) {
            *(v8bf*)&u.s.A[sr + i * 32][sc] = *(const v8bf*)(ag + (size_t)i * 32 * 1024 + kt * 64);
            *(v8bf*)&u.s.B[sr + i * 32][sc] = *(const v8bf*)(bg + (size_t)i * 32 * 1024 + kt * 64);
        }
        __syncthreads();
        v8bf a[2][4], b[2][4];
        #pragma unroll
        for (int ks = 0; ks < 2; ++ks) {
            #pragma unroll
            for (int im = 0; im < 4; ++im)
                a[ks][im] = *(const v8bf*)&u.s.A[wm * 64 + im * 16 + l15][ks * 32 + q * 8];
            #pragma unroll
            for (int in = 0; in < 4; ++in)
                b[ks][in] = *(const v8bf*)&u.s.B[wn * 64 + in * 16 + l15][ks * 32 + q * 8];
        }
        #pragma unroll
        for (int ks = 0; ks < 2; ++ks)
            #pragma unroll
            for (int im = 0; im < 4; ++im)
                #pragma unroll
                for (int in = 0; in < 4; ++in)
                    acc[im][in] = __builtin_amdgcn_mfma_f32_16x16x32_bf16(
                        a[ks][im], b[ks][in], acc[im][in], 0, 0, 0);
    }
    __syncthreads();
    #pragma unroll
    for (int in = 0; in < 4; ++in) {
        const int nl = wn * 64 + in * 16 + l15;
        const float bv = biasp[n0 + nl];
        #pragma unroll
        for (int im = 0; im < 4; ++im)
            #pragma unroll
            for (int r = 0; r < 4; ++r)
                u.C[wm * 64 + im * 16 + q * 4 + r][nl] = (__bf16)(acc[im][in][r] + bv);
    }
    __syncthreads();
    const int cr = tid >> 1, chf = (tid & 1) * 64;
    __bf16* outp = xg + ((size_t)(t0 + cr) * 128 + bb) * 4096 + n0 + chf;
    #pragma unroll
    for (int j = 0; j < 8; ++j)
        *(uint4*)(outp + j * 8) = *(const uint4*)&u.C[cr][chf + j * 8];
}

// fallback (fp32 A staging, BK=32) -- known-good from R1/R2, used only if
// ws_size can't hold the bf16 copy of x.
__global__ __launch_bounds__(256) void gemm_xg_f32(
    const float* __restrict__ x, const __bf16* __restrict__ wih,
    const float* __restrict__ biasp, __bf16* __restrict__ xg)
{
    const int bx = blockIdx.x;
    const int mtile = bx >> 5, ntile = bx & 31;
    const int m0 = mtile << 7, n0 = ntile << 7;
    const int bb = mtile >> 2, t0 = (mtile & 3) << 7;
    const int tid = threadIdx.x;
    const int lane = tid & 63, wave = tid >> 6;
    const int wm = wave >> 1, wn = wave & 1;
    const int l15 = lane & 15, q = lane >> 4;

    __shared__ __bf16 Al[128][40];
    __shared__ __bf16 Bl[128][40];
    v4f acc[4][4] = {};

    for (int kt = 0; kt < 32; ++kt) {
        __syncthreads();
        const int k0 = kt * 32;
        #pragma unroll
        for (int i = 0; i < 4; ++i) {
            const int s = tid + i * 256, r = s >> 3, c = s & 7;
            const float4 v = *(const float4*)&x[(size_t)(m0 + r) * 1024 + k0 + c * 4];
            v4bf pk = { (__bf16)v.x, (__bf16)v.y, (__bf16)v.z, (__bf16)v.w };
            *(v4bf*)&Al[r][c * 4] = pk;
        }
        #pragma unroll
        for (int j = 0; j < 2; ++j) {
            const int s = tid + j * 256, r = s >> 2, ch = s & 3;
            const uint4 v = *(const uint4*)&wih[(size_t)(n0 + r) * 1024 + k0 + ch * 8];
            *(uint4*)&Bl[r][ch * 8] = v;
        }
        __syncthreads();
        v8bf a[4], b[4];
        #pragma unroll
        for (int im = 0; im < 4; ++im) a[im] = *(const v8bf*)&Al[wm * 64 + im * 16 + l15][q * 8];
        #pragma unroll
        for (int in = 0; in < 4; ++in) b[in] = *(const v8bf*)&Bl[wn * 64 + in * 16 + l15][q * 8];
        #pragma unroll
        for (int im = 0; im < 4; ++im)
            #pragma unroll
            for (int in = 0; in < 4; ++in)
                acc[im][in] = __builtin_amdgcn_mfma_f32_16x16x32_bf16(a[im], b[in], acc[im][in], 0, 0, 0);
    }
    #pragma unroll
    for (int in = 0; in < 4; ++in) {
        const int nl = wn * 64 + in * 16 + l15;
        const float bv = biasp[n0 + nl];
        #pragma unroll
        for (int im = 0; im < 4; ++im) {
            const int mbase = wm * 64 + im * 16 + q * 4;
            #pragma unroll
            for (int r = 0; r < 4; ++r)
                xg[((size_t)(t0 + mbase + r) * 128 + bb) * 4096 + n0 + nl] =
                    (__bf16)(acc[im][in][r] + bv);
        }
    }
}

// ---------------------------------------------------------------------------
// lstm_rec v3 (see header comment)
// ---------------------------------------------------------------------------
__device__ __forceinline__ v8bf ld_frag_sc1(const unsigned long long* p) {
    union { unsigned long long u[2]; v8bf v; } c;
    c.u[0] = __hip_atomic_load(p,     __ATOMIC_RELAXED, __HIP_MEMORY_SCOPE_AGENT);
    c.u[1] = __hip_atomic_load(p + 1, __ATOMIC_RELAXED, __HIP_MEMORY_SCOPE_AGENT);
    return c.v;
}
__device__ __forceinline__ float sigm_f(float x) {
    return __builtin_amdgcn_rcpf(1.f + __expf(-x));
}
__device__ __forceinline__ float tanh_f(float x) {
    return 1.f - 2.f * __builtin_amdgcn_rcpf(__expf(2.f * x) + 1.f);
}

__global__ __launch_bounds__(256, 1) void lstm_rec(
    const __bf16* __restrict__ whh, const __bf16* __restrict__ xg,
    const float* __restrict__ c0, __bf16* __restrict__ hbuf, int* flags)
{
    const int tid  = threadIdx.x;
    const int lane = tid & 63, kw = tid >> 6;   // wave = K-slice (256 k)
    const int in   = blockIdx.x & 63;           // n-tile: 64 gates = 16 h cols
    const int mq   = blockIdx.x >> 6;           // m-quarter: 32 batch rows
    const int l15  = lane & 15, q = lane >> 4;

    __shared__ float pbuf[4][32][68];

    // ---- w_hh tile -> registers, once ----
    v8bf breg[4][8];
    {
        const __bf16* wb = whh + ((size_t)in * 64) * 1024 + kw * 256;
        #pragma unroll
        for (int nf = 0; nf < 4; ++nf)
            #pragma unroll
            for (int ks = 0; ks < 8; ++ks)
                breg[nf][ks] = *(const v8bf*)&wb[(size_t)(nf * 16 + l15) * 1024 + ks * 32 + q * 8];
    }

    const int em  = tid >> 3;                   // 0..31
    const int ehc = (tid & 7) * 2;              // 0..14
    const int mG  = mq * 32 + em;
    const int jG  = in * 16 + ehc;
    float2 cv = *(const float2*)&c0[(size_t)mG * 1024 + jG];

    const size_t rb0 = (size_t)(mq * 32 + l15) * 256 + (size_t)kw * 64 + q * 2; // 8B units
    const size_t rb1 = rb0 + 16 * 256;

    #pragma unroll 1
    for (int t = 1; t <= 512; ++t) {
        // prefetch xg for this step (overlaps the flag wait)
        v2bf xpre[4];
        {
            const __bf16* xgp = xg + ((size_t)(t - 1) * 128 + mG) * 4096 + in * 64;
            #pragma unroll
            for (int g = 0; g < 4; ++g) xpre[g] = *(const v2bf*)&xgp[g * 16 + ehc];
        }

        // ---- per-wave poll: 64 producer flags of this m-quarter ----
        {
            const int* fp = flags + (size_t)(t - 1) * 256 + (mq << 6) + lane;
            while (__ballot(__hip_atomic_load(fp, __ATOMIC_RELAXED,
                                              __HIP_MEMORY_SCOPE_AGENT) != 0)
                   != 0xFFFFFFFFFFFFFFFFull) { }
        }

        const unsigned long long* hq =
            (const unsigned long long*)(hbuf + (size_t)((t - 1) & 1) * 131072);

        v8bf af[2][8];
        #pragma unroll
        for (int ks = 0; ks < 8; ++ks) {
            af[0][ks] = ld_frag_sc1(hq + rb0 + ks * 8);
            af[1][ks] = ld_frag_sc1(hq + rb1 + ks * 8);
        }

        v4f acc[2][4] = {};
        #pragma unroll
        for (int ks = 0; ks < 8; ++ks)
            #pragma unroll
            for (int mh = 0; mh < 2; ++mh)
                #pragma unroll
                for (int nf = 0; nf < 4; ++nf)
                    acc[mh][nf] = __builtin_amdgcn_mfma_f32_16x16x32_bf16(
                        af[mh][ks], breg[nf][ks], acc[mh][nf], 0, 0, 0);

        #pragma unroll
        for (int mh = 0; mh < 2; ++mh)
            #pragma unroll
            for (int nf = 0; nf < 4; ++nf)
                #pragma unroll
                for (int r = 0; r < 4; ++r)
                    pbuf[kw][mh * 16 + q * 4 + r][nf * 16 + l15] = acc[mh][nf][r];
        __syncthreads();

        float2 gsum[4];
        #pragma unroll
        for (int g = 0; g < 4; ++g) {
            float2 s = *(const float2*)&pbuf[0][em][g * 16 + ehc];
            #pragma unroll
            for (int k2 = 1; k2 < 4; ++k2) {
                const float2 p2 = *(const float2*)&pbuf[k2][em][g * 16 + ehc];
                s.x += p2.x; s.y += p2.y;
            }
            s.x += (float)xpre[g][0];
            s.y += (float)xpre[g][1];
            gsum[g] = s;
        }

        cv.x = sigm_f(gsum[1].x) * cv.x + sigm_f(gsum[0].x) * tanh_f(gsum[2].x);
        cv.y = sigm_f(gsum[1].y) * cv.y + sigm_f(gsum[0].y) * tanh_f(gsum[2].y);
        const float hx = sigm_f(gsum[3].x) * tanh_f(cv.x);
        const float hy = sigm_f(gsum[3].y) * tanh_f(cv.y);

        union { __bf16 b[2]; unsigned u; } hp;
        hp.b[0] = (__bf16)hx; hp.b[1] = (__bf16)hy;
        __hip_atomic_store(
            (unsigned*)(hbuf + (size_t)(t & 1) * 131072 + (size_t)mG * 1024 + jG),
            hp.u, __ATOMIC_RELAXED, __HIP_MEMORY_SCOPE_AGENT);

        __syncthreads();   // vmcnt(0): all h-stores of this block drained to L3
        if (tid == 0)
            __hip_atomic_store(&flags[(size_t)t * 256 + (mq << 6) + in], 1,
                               __ATOMIC_RELAXED, __HIP_MEMORY_SCOPE_AGENT);
    }
}

// ---------------------------------------------------------------------------
__global__ __launch_bounds__(256) void fc_out(
    const __bf16* __restrict__ hb, const float* __restrict__ wfc,
    const float* __restrict__ bfc, float* __restrict__ out)
{
    const int b = blockIdx.x, o = threadIdx.x;
    __shared__ float hs[1024];
    for (int i = threadIdx.x; i < 1024; i += 256) hs[i] = (float)hb[(size_t)b * 1024 + i];
    __syncthreads();
    const float* wr = wfc + (size_t)o * 1024;
    float s = 0.f;
    for (int k = 0; k < 1024; k += 4) {
        const float4 w = *(const float4*)&wr[k];
        s += hs[k] * w.x + hs[k + 1] * w.y + hs[k + 2] * w.z + hs[k + 3] * w.w;
    }
    out[b * 256 + o] = s + bfc[o];
}

// ---------------------------------------------------------------------------
extern "C" void kernel_launch(void* const* d_in, const int* in_sizes, int n_in,
                              void* d_out, int out_size, void* d_ws, size_t ws_size,
                              hipStream_t stream) {
    (void)in_sizes; (void)n_in; (void)out_size;
    const float* x    = (const float*)d_in[0];
    const float* h0   = (const float*)d_in[1];
    const float* c0   = (const float*)d_in[2];
    const float* w_ih = (const float*)d_in[3];
    const float* w_hh = (const float*)d_in[4];
    const float* bias = (const float*)d_in[5];
    const float* w_fc = (const float*)d_in[6];
    const float* b_fc = (const float*)d_in[7];
    float* out = (float*)d_out;

    char* ws = (char*)d_ws;
    __bf16* xg    = (__bf16*)(ws);
    __bf16* w_ihp = (__bf16*)(ws + WIHP_O);
    __bf16* w_hhp = (__bf16*)(ws + WHHP_O);
    float*  biasp = (float*)(ws + BIASP_O);
    __bf16* hbuf  = (__bf16*)(ws + HBUF_O);
    int*    flags = (int*)(ws + FLAGS_O);
    __bf16* xb    = (__bf16*)(ws + XB_O);

    prep_kernel<<<16384, 256, 0, stream>>>(w_ih, w_hh, bias, h0, w_ihp, w_hhp, biasp, hbuf, flags);
    if (ws_size >= WS_FULL) {
        xcast<<<32768, 256, 0, stream>>>(x, xb);
        gemm_xg_bf16<<<16384, 256, 0, stream>>>(xb, w_ihp, biasp, xg);
    } else {
        gemm_xg_f32<<<16384, 256, 0, stream>>>(x, w_ihp, biasp, xg);
    }
    lstm_rec<<<NBLK_REC, 256, 0, stream>>>(w_hhp, xg, c0, hbuf, flags);
    fc_out<<<128, 256, 0, stream>>>(hbuf, w_fc, b_fc, out);
}

// Round 4
// 4455.330 us; speedup vs baseline: 2.7669x; 1.3386x over previous
//
#include <hip/hip_runtime.h>
#include <hip/hip_bf16.h>

// ---------------------------------------------------------------------------
// LSTM (B=128, T=512, I=H=1024) + final FC (O=256) on gfx950.
// prep -> xcast -> gemm_xg (bf16, time-major, gate-interleaved cols) ->
// lstm_rec v4 -> fc_out.
//
// lstm_rec v4: 128 persistent blocks = 4 m-quarters x 32 n-blocks.
// Block = 32 batch rows x 32 h-cols; wave = 8 h-cols (N-split), K=1024 whole.
// w_hh slice lives ENTIRELY in VGPRs (256/lane, 1 wave/SIMD). h exchanged as
// self-validating tagged granules {h0,h1,tag=t} stored with ONE relaxed
// agent(sc1) 8B atomic store -- no fences (R1: L2 walks ~19us/step), no flag
// array (R2/R3: hot-line congestion + 4 serialized L3 trips ~9us/step).
// Consumers poll-load the granules they need; tag mismatch -> retry.
// One __syncthreads per step. Gate layout per wave: permuted row
// n = ns*128 + w*32 + g*8 + jl  <->  orig g*1024 + (ns*32 + w*8 + jl).
// ---------------------------------------------------------------------------

typedef float  v4f  __attribute__((ext_vector_type(4)));
typedef __bf16 v8bf __attribute__((ext_vector_type(8)));
typedef __bf16 v4bf __attribute__((ext_vector_type(4)));

#define NBLK_REC 128

// ---------------- workspace layout (bytes) ----------------
static constexpr size_t XG_B    = (size_t)512 * 128 * 4096 * 2;      // 512 MiB
static constexpr size_t WIHP_O  = XG_B;
static constexpr size_t WHHP_O  = WIHP_O + (size_t)4096 * 1024 * 2;
static constexpr size_t BIASP_O = WHHP_O + (size_t)4096 * 1024 * 2;
static constexpr size_t HBUF_O  = BIASP_O + 16384;                   // 2*512KiB u64 granules
static constexpr size_t XB_O    = HBUF_O + (size_t)2 * 128 * 512 * 8;
static constexpr size_t WS_FULL = XB_O + (size_t)128 * 512 * 1024 * 2;

__device__ __forceinline__ float bf2f(unsigned short u) {
    union { unsigned u32; float f; } c; c.u32 = (unsigned)u << 16; return c.f;
}

// ---------------------------------------------------------------------------
// prep: permute+convert weights, tagged h0 granules, scrub parity-1 tags
// permutation: n = ns*128 + w*32 + g*8 + jl ; hcol = ns*32 + w*8 + jl
//              orig row = g*1024 + hcol
// ---------------------------------------------------------------------------
__global__ __launch_bounds__(256) void prep_kernel(
    const float* __restrict__ w_ih, const float* __restrict__ w_hh,
    const float* __restrict__ bias, const float* __restrict__ h0,
    __bf16* __restrict__ w_ihp, __bf16* __restrict__ w_hhp,
    float* __restrict__ biasp, unsigned long long* __restrict__ hb,
    int* __restrict__ unused)
{
    const int idx = blockIdx.x * 256 + threadIdx.x;       // 0 .. 4194303
    const int n = idx >> 10, k = idx & 1023;
    const int hcol = (n >> 7) * 32 + ((n >> 5) & 3) * 8 + (n & 7);
    const int g = (n >> 3) & 3;
    const int on = g * 1024 + hcol;
    w_ihp[idx] = (__bf16)w_ih[(size_t)on * 1024 + k];
    w_hhp[idx] = (__bf16)w_hh[(size_t)on * 1024 + k];
    if (idx < 4096) {
        const int hc2 = (idx >> 7) * 32 + ((idx >> 5) & 3) * 8 + (idx & 7);
        biasp[idx] = bias[((idx >> 3) & 3) * 1024 + hc2];
    }
    if (idx < 128 * 512) {   // tagged h0 granules, tag=0 (parity-0 buffer)
        const int m = idx >> 9, jp = idx & 511;
        union { __bf16 b; unsigned short u; } c0h, c1h;
        c0h.b = (__bf16)h0[(size_t)m * 1024 + jp * 2];
        c1h.b = (__bf16)h0[(size_t)m * 1024 + jp * 2 + 1];
        hb[idx] = (unsigned long long)c0h.u | ((unsigned long long)c1h.u << 16);
        hb[65536 + idx] = 0xFFFFull << 32;   // parity-1: never-matching tag
    }
    (void)unused;
}

// ---------------------------------------------------------------------------
__global__ __launch_bounds__(256) void xcast(
    const float* __restrict__ x, __bf16* __restrict__ xb)
{
    const size_t i = ((size_t)blockIdx.x * 256 + threadIdx.x) * 8;
    const float4 a = *(const float4*)&x[i];
    const float4 b = *(const float4*)&x[i + 4];
    v8bf o = { (__bf16)a.x, (__bf16)a.y, (__bf16)a.z, (__bf16)a.w,
               (__bf16)b.x, (__bf16)b.y, (__bf16)b.z, (__bf16)b.w };
    *(v8bf*)&xb[i] = o;
}

// ---------------------------------------------------------------------------
// gemm_xg (bf16): xg[t][b][hcol][g] = bf16( xb . w_ihp + biasp ), gate-
// interleaved columns. Tile 128x128, 4 waves 2x2, BK=64, LDS epilogue.
// col remap inside tile: nl(permuted) -> outl = (w*8+jl)*4 + g.
// ---------------------------------------------------------------------------
__global__ __launch_bounds__(256) void gemm_xg_bf16(
    const __bf16* __restrict__ xb, const __bf16* __restrict__ wih,
    const float* __restrict__ biasp, __bf16* __restrict__ xg)
{
    const int bx = blockIdx.x;
    const int mtile = bx >> 5, ntile = bx & 31;
    const int m0 = mtile << 7, n0 = ntile << 7;
    const int bb = mtile >> 2, t0 = (mtile & 3) << 7;
    const int tid = threadIdx.x;
    const int lane = tid & 63, wave = tid >> 6;
    const int wm = wave >> 1, wn = wave & 1;
    const int l15 = lane & 15, q = lane >> 4;

    __shared__ union {
        struct { __bf16 A[128][72]; __bf16 B[128][72]; } s;
        __bf16 C[128][132];
    } u;

    const int sr = tid >> 3, sc = (tid & 7) * 8;
    const __bf16* ag = xb  + (size_t)(m0 + sr) * 1024 + sc;
    const __bf16* bg = wih + (size_t)(n0 + sr) * 1024 + sc;

    v4f acc[4][4] = {};
    for (int kt = 0; kt < 16; ++kt) {
        __syncthreads();
        #pragma unroll
        for (int i = 0; i < 4; ++i) {
            *(v8bf*)&u.s.A[sr + i * 32][sc] = *(const v8bf*)(ag + (size_t)i * 32 * 1024 + kt * 64);
            *(v8bf*)&u.s.B[sr + i * 32][sc] = *(const v8bf*)(bg + (size_t)i * 32 * 1024 + kt * 64);
        }
        __syncthreads();
        v8bf a[2][4], b[2][4];
        #pragma unroll
        for (int ks = 0; ks < 2; ++ks) {
            #pragma unroll
            for (int im = 0; im < 4; ++im)
                a[ks][im] = *(const v8bf*)&u.s.A[wm * 64 + im * 16 + l15][ks * 32 + q * 8];
            #pragma unroll
            for (int in_ = 0; in_ < 4; ++in_)
                b[ks][in_] = *(const v8bf*)&u.s.B[wn * 64 + in_ * 16 + l15][ks * 32 + q * 8];
        }
        #pragma unroll
        for (int ks = 0; ks < 2; ++ks)
            #pragma unroll
            for (int im = 0; im < 4; ++im)
                #pragma unroll
                for (int in_ = 0; in_ < 4; ++in_)
                    acc[im][in_] = __builtin_amdgcn_mfma_f32_16x16x32_bf16(
                        a[ks][im], b[ks][in_], acc[im][in_], 0, 0, 0);
    }
    __syncthreads();
    #pragma unroll
    for (int in_ = 0; in_ < 4; ++in_) {
        const int nl = wn * 64 + in_ * 16 + l15;
        const int outl = (((nl >> 5) * 8 + (nl & 7)) << 2) | ((nl >> 3) & 3);
        const float bv = biasp[n0 + nl];
        #pragma unroll
        for (int im = 0; im < 4; ++im)
            #pragma unroll
            for (int r = 0; r < 4; ++r)
                u.C[wm * 64 + im * 16 + q * 4 + r][outl] = (__bf16)(acc[im][in_][r] + bv);
    }
    __syncthreads();
    const int cr = tid >> 1, chf = (tid & 1) * 64;
    __bf16* outp = xg + ((size_t)(t0 + cr) * 128 + bb) * 4096 + n0 + chf;
    #pragma unroll
    for (int j = 0; j < 8; ++j)
        *(uint4*)(outp + j * 8) = *(const uint4*)&u.C[cr][chf + j * 8];
}

// fallback: fp32 A staging (used only if ws too small for xb)
__global__ __launch_bounds__(256) void gemm_xg_f32(
    const float* __restrict__ x, const __bf16* __restrict__ wih,
    const float* __restrict__ biasp, __bf16* __restrict__ xg)
{
    const int bx = blockIdx.x;
    const int mtile = bx >> 5, ntile = bx & 31;
    const int m0 = mtile << 7, n0 = ntile << 7;
    const int bb = mtile >> 2, t0 = (mtile & 3) << 7;
    const int tid = threadIdx.x;
    const int lane = tid & 63, wave = tid >> 6;
    const int wm = wave >> 1, wn = wave & 1;
    const int l15 = lane & 15, q = lane >> 4;

    __shared__ __bf16 Al[128][40];
    __shared__ __bf16 Bl[128][40];
    v4f acc[4][4] = {};

    for (int kt = 0; kt < 32; ++kt) {
        __syncthreads();
        const int k0 = kt * 32;
        #pragma unroll
        for (int i = 0; i < 4; ++i) {
            const int s = tid + i * 256, r = s >> 3, c = s & 7;
            const float4 v = *(const float4*)&x[(size_t)(m0 + r) * 1024 + k0 + c * 4];
            v4bf pk = { (__bf16)v.x, (__bf16)v.y, (__bf16)v.z, (__bf16)v.w };
            *(v4bf*)&Al[r][c * 4] = pk;
        }
        #pragma unroll
        for (int j = 0; j < 2; ++j) {
            const int s = tid + j * 256, r = s >> 2, ch = s & 3;
            const uint4 v = *(const uint4*)&wih[(size_t)(n0 + r) * 1024 + k0 + ch * 8];
            *(uint4*)&Bl[r][ch * 8] = v;
        }
        __syncthreads();
        v8bf a[4], b[4];
        #pragma unroll
        for (int im = 0; im < 4; ++im) a[im] = *(const v8bf*)&Al[wm * 64 + im * 16 + l15][q * 8];
        #pragma unroll
        for (int in_ = 0; in_ < 4; ++in_) b[in_] = *(const v8bf*)&Bl[wn * 64 + in_ * 16 + l15][q * 8];
        #pragma unroll
        for (int im = 0; im < 4; ++im)
            #pragma unroll
            for (int in_ = 0; in_ < 4; ++in_)
                acc[im][in_] = __builtin_amdgcn_mfma_f32_16x16x32_bf16(a[im], b[in_], acc[im][in_], 0, 0, 0);
    }
    #pragma unroll
    for (int in_ = 0; in_ < 4; ++in_) {
        const int nl = wn * 64 + in_ * 16 + l15;
        const int outl = (((nl >> 5) * 8 + (nl & 7)) << 2) | ((nl >> 3) & 3);
        const float bv = biasp[n0 + nl];
        #pragma unroll
        for (int im = 0; im < 4; ++im) {
            const int mbase = wm * 64 + im * 16 + q * 4;
            #pragma unroll
            for (int r = 0; r < 4; ++r)
                xg[((size_t)(t0 + mbase + r) * 128 + bb) * 4096 + n0 + outl] =
                    (__bf16)(acc[im][in_][r] + bv);
        }
    }
}

// ---------------------------------------------------------------------------
// lstm_rec v4
// ---------------------------------------------------------------------------
__device__ __forceinline__ float sigm_f(float x) {
    return __builtin_amdgcn_rcpf(1.f + __expf(-x));
}
__device__ __forceinline__ float tanh_f(float x) {
    return 1.f - 2.f * __builtin_amdgcn_rcpf(__expf(2.f * x) + 1.f);
}

__global__ __launch_bounds__(256, 1) void lstm_rec(
    const __bf16* __restrict__ whh, const __bf16* __restrict__ xg,
    const float* __restrict__ c0, unsigned long long* hbuf)
{
    const int tid  = threadIdx.x;
    const int lane = tid & 63, w = tid >> 6;
    const int l15  = lane & 15, q = lane >> 4;
    const int mq   = blockIdx.x >> 5;   // quarter (32 batch rows)
    const int ns   = blockIdx.x & 31;   // n-block (32 h-cols)

    __shared__ __bf16 hA[2][32][1032];  // staged h(t-1), padded pitch (132 KiB)

    // ---- w_hh slice -> VGPRs (wave w: 32 gate rows x 1024 k = 256 VGPR) ----
    v8bf breg[2][32];
    {
        const __bf16* wb = whh + (size_t)(ns * 128 + w * 32) * 1024;
        #pragma unroll
        for (int ni = 0; ni < 2; ++ni)
            #pragma unroll
            for (int kc = 0; kc < 32; ++kc)
                breg[ni][kc] = *(const v8bf*)&wb[(size_t)(ni * 16 + l15) * 1024 + kc * 32 + q * 8];
    }

    // epilogue identity: lane handles (mi rows-half, h-col j)
    const int j    = l15 & 7;
    const int mi   = (l15 >> 3) & 1;
    const int hcol = ns * 32 + w * 8 + j;
    const int row0 = mi * 16 + q * 4;          // local rows row0..row0+3
    float c_[4];
    #pragma unroll
    for (int r = 0; r < 4; ++r)
        c_[r] = c0[(size_t)(mq * 32 + row0 + r) * 1024 + hcol];

    #pragma unroll 1
    for (int t = 1; t <= 512; ++t) {
        const int par  = (t - 1) & 1;
        const unsigned short want = (unsigned short)(t - 1);

        // ---- xg prefetch (plain loads, gate-interleaved granules) ----
        unsigned long long xq[4];
        {
            const unsigned long long* xp = (const unsigned long long*)xg
                + ((size_t)(t - 1) * 128 + mq * 32 + row0) * 1024 + hcol;
            #pragma unroll
            for (int r = 0; r < 4; ++r) xq[r] = xp[(size_t)r * 1024];
        }

        // ---- phase 1: cooperative tagged load of h(t-1) -> LDS ----
        {
            const unsigned long long* hq = hbuf + (size_t)par * 65536;
            #pragma unroll 1
            for (int r2 = 0; r2 < 8; ++r2) {
                const int rowl = w * 8 + r2;
                const unsigned long long* base = hq + (size_t)(mq * 32 + rowl) * 512;
                unsigned long long gv[8];
                #pragma unroll
                for (int c = 0; c < 8; ++c)
                    gv[c] = __hip_atomic_load(base + c * 64 + lane,
                                              __ATOMIC_RELAXED, __HIP_MEMORY_SCOPE_AGENT);
                for (;;) {
                    bool ok = true;
                    #pragma unroll
                    for (int c = 0; c < 8; ++c)
                        ok &= ((unsigned short)(gv[c] >> 32) == want);
                    if (ok) break;
                    #pragma unroll
                    for (int c = 0; c < 8; ++c)
                        gv[c] = __hip_atomic_load(base + c * 64 + lane,
                                                  __ATOMIC_RELAXED, __HIP_MEMORY_SCOPE_AGENT);
                }
                #pragma unroll
                for (int c = 0; c < 8; ++c)
                    *(unsigned*)&hA[par][rowl][(c * 64 + lane) * 2] = (unsigned)gv[c];
            }
        }
        __syncthreads();   // the ONLY barrier per step

        // ---- phase 2: MFMA  (A from LDS, B from VGPRs) ----
        v4f acc[2][2] = {};
        #pragma unroll
        for (int kc = 0; kc < 32; ++kc) {
            const v8bf a0 = *(const v8bf*)&hA[par][l15][kc * 32 + q * 8];
            const v8bf a1 = *(const v8bf*)&hA[par][l15 + 16][kc * 32 + q * 8];
            acc[0][0] = __builtin_amdgcn_mfma_f32_16x16x32_bf16(a0, breg[0][kc], acc[0][0], 0, 0, 0);
            acc[0][1] = __builtin_amdgcn_mfma_f32_16x16x32_bf16(a0, breg[1][kc], acc[0][1], 0, 0, 0);
            acc[1][0] = __builtin_amdgcn_mfma_f32_16x16x32_bf16(a1, breg[0][kc], acc[1][0], 0, 0, 0);
            acc[1][1] = __builtin_amdgcn_mfma_f32_16x16x32_bf16(a1, breg[1][kc], acc[1][1], 0, 0, 0);
        }

        // ---- phase 3: gate assembly via shfl_xor(8), cell, tagged h store ----
        v4f s0 = mi ? acc[0][0] : acc[1][0];
        v4f s1 = mi ? acc[0][1] : acc[1][1];
        v4f r0, r1;
        #pragma unroll
        for (int r = 0; r < 4; ++r) {
            r0[r] = __shfl_xor(s0[r], 8);
            r1[r] = __shfl_xor(s1[r], 8);
        }
        const v4f own0 = mi ? acc[1][0] : acc[0][0];
        const v4f own1 = mi ? acc[1][1] : acc[0][1];

        unsigned hw[4];
        #pragma unroll
        for (int r = 0; r < 4; ++r) {
            const float iv = (mi ? r0[r]   : own0[r]) + bf2f((unsigned short)(xq[r]));
            const float fv = (mi ? own0[r] : r0[r])   + bf2f((unsigned short)(xq[r] >> 16));
            const float gv = (mi ? r1[r]   : own1[r]) + bf2f((unsigned short)(xq[r] >> 32));
            const float ov = (mi ? own1[r] : r1[r])   + bf2f((unsigned short)(xq[r] >> 48));
            c_[r] = sigm_f(fv) * c_[r] + sigm_f(iv) * tanh_f(gv);
            const float hv = sigm_f(ov) * tanh_f(c_[r]);
            union { __bf16 b; unsigned short u; } cv; cv.b = (__bf16)hv;
            hw[r] = cv.u;
        }
        // pair columns (j even keeps low, partner j+1 supplies high)
        unsigned long long* hd = hbuf + (size_t)(t & 1) * 65536
                               + (size_t)(mq * 32 + row0) * 512 + (hcol >> 1);
        #pragma unroll
        for (int r = 0; r < 4; ++r) {
            const unsigned ph = __shfl_xor(hw[r], 1);
            if ((j & 1) == 0) {
                const unsigned long long wrd = (unsigned long long)(hw[r] | (ph << 16))
                                             | ((unsigned long long)(unsigned short)t << 32);
                __hip_atomic_store(hd + (size_t)r * 512, wrd,
                                   __ATOMIC_RELAXED, __HIP_MEMORY_SCOPE_AGENT);
            }
        }
    }
}

// ---------------------------------------------------------------------------
// fc_out: out[b][o] = h_last[b] . w_fc[o] + b_fc[o]  (h_last: tagged granules,
// parity-0 buffer since t=512 is even)
// ---------------------------------------------------------------------------
__global__ __launch_bounds__(256) void fc_out(
    const unsigned long long* __restrict__ hb, const float* __restrict__ wfc,
    const float* __restrict__ bfc, float* __restrict__ out)
{
    const int b = blockIdx.x, o = threadIdx.x;
    __shared__ float hs[1024];
    for (int i = threadIdx.x; i < 512; i += 256) {
        const unsigned long long g = hb[(size_t)b * 512 + i];
        hs[2 * i]     = bf2f((unsigned short)g);
        hs[2 * i + 1] = bf2f((unsigned short)(g >> 16));
    }
    __syncthreads();
    const float* wr = wfc + (size_t)o * 1024;
    float s = 0.f;
    for (int k = 0; k < 1024; k += 4) {
        const float4 w = *(const float4*)&wr[k];
        s += hs[k] * w.x + hs[k + 1] * w.y + hs[k + 2] * w.z + hs[k + 3] * w.w;
    }
    out[b * 256 + o] = s + bfc[o];
}

// ---------------------------------------------------------------------------
extern "C" void kernel_launch(void* const* d_in, const int* in_sizes, int n_in,
                              void* d_out, int out_size, void* d_ws, size_t ws_size,
                              hipStream_t stream) {
    (void)in_sizes; (void)n_in; (void)out_size;
    const float* x    = (const float*)d_in[0];
    const float* h0   = (const float*)d_in[1];
    const float* c0   = (const float*)d_in[2];
    const float* w_ih = (const float*)d_in[3];
    const float* w_hh = (const float*)d_in[4];
    const float* bias = (const float*)d_in[5];
    const float* w_fc = (const float*)d_in[6];
    const float* b_fc = (const float*)d_in[7];
    float* out = (float*)d_out;

    char* ws = (char*)d_ws;
    __bf16* xg    = (__bf16*)(ws);
    __bf16* w_ihp = (__bf16*)(ws + WIHP_O);
    __bf16* w_hhp = (__bf16*)(ws + WHHP_O);
    float*  biasp = (float*)(ws + BIASP_O);
    unsigned long long* hbuf = (unsigned long long*)(ws + HBUF_O);
    __bf16* xb    = (__bf16*)(ws + XB_O);

    prep_kernel<<<16384, 256, 0, stream>>>(w_ih, w_hh, bias, h0, w_ihp, w_hhp, biasp, hbuf, nullptr);
    if (ws_size >= WS_FULL) {
        xcast<<<32768, 256, 0, stream>>>(x, xb);
        gemm_xg_bf16<<<16384, 256, 0, stream>>>(xb, w_ihp, biasp, xg);
    } else {
        gemm_xg_f32<<<16384, 256, 0, stream>>>(x, w_ihp, biasp, xg);
    }
    lstm_rec<<<NBLK_REC, 256, 0, stream>>>(w_hhp, xg, c0, hbuf);
    fc_out<<<128, 256, 0, stream>>>(hbuf, w_fc, b_fc, out);
}